// Round 16
// baseline (3538.050 us; speedup 1.0000x reference)
//
#include <hip/hip_runtime.h>
#include <math.h>

#define STEPS 256
#define BATCH 128
#define HALF_M 64
#define INSZ  512
#define H1SZ  1536
#define H2SZ  1536
#define NOUT  512
#define K1    2048   // INSZ + H1SZ
#define K2    3072   // H1SZ + H2SZ
#define NC1   48     // col-blocks per half (32 cols each)
#define NC2   48
#define NC3   16
#define NBLK  224    // 2 halves * (48+48+16)
#define RING  8

typedef short bf16x8 __attribute__((ext_vector_type(8)));
typedef float f32x4  __attribute__((ext_vector_type(4)));
typedef unsigned short u16;

__device__ __forceinline__ f32x4 mfma16(bf16x8 a, bf16x8 b, f32x4 c) {
  return __builtin_amdgcn_mfma_f32_16x16x32_bf16(a, b, c, 0, 0, 0);
}

__device__ __forceinline__ u16 f2bf(float f) {
  unsigned u = __builtin_bit_cast(unsigned, f);
  u += 0x7fffu + ((u >> 16) & 1u);
  return (u16)(u >> 16);
}

// 8 fp32 -> bf16x8 (RTNE) via packed cvt (register-only asm)
__device__ __forceinline__ bf16x8 cvt8(const float* p) {
  f32x4 lo = *(const f32x4*)p;
  f32x4 hi = *(const f32x4*)(p + 4);
  union { unsigned u[4]; bf16x8 v; } r;
  asm("v_cvt_pk_bf16_f32 %0, %1, %2" : "=v"(r.u[0]) : "v"(lo[0]), "v"(lo[1]));
  asm("v_cvt_pk_bf16_f32 %0, %1, %2" : "=v"(r.u[1]) : "v"(lo[2]), "v"(lo[3]));
  asm("v_cvt_pk_bf16_f32 %0, %1, %2" : "=v"(r.u[2]) : "v"(hi[0]), "v"(hi[1]));
  asm("v_cvt_pk_bf16_f32 %0, %1, %2" : "=v"(r.u[3]) : "v"(hi[2]), "v"(hi[3]));
  return r.v;
}

// ---- sealed async-load region primitives ----
#define LOAD_SC_OFS(dst, ptr, ofs) \
  asm volatile("global_load_dwordx4 %0, %1, off offset:%2 sc0 sc1" \
               : "=v"(dst) : "v"(ptr), "i"(ofs) : "memory")
#define STORE_SC(ptr, val) \
  asm volatile("global_store_dwordx4 %0, %1, off sc0 sc1" :: "v"(ptr), "v"(val) : "memory")
#define WAITV(n) asm volatile("s_waitcnt vmcnt(" #n ")" ::: "memory")
#define PIN4(v)  asm volatile("" : "+v"(v))
#define PINA(v)  asm volatile("" : "+a"(v))      // force value into AGPRs
// MFMA with B-operand in AGPR (frees VGPR budget); C/D chained in VGPR
#define MFMA_AB(acc, va, ab) \
  asm volatile("v_mfma_f32_16x16x32_bf16 %0, %1, %2, %0" : "+v"(acc) : "v"(va), "a"(ab))
#define MFMA_FENCE() asm volatile("s_nop 7\n\ts_nop 7\n\ts_nop 7")

__device__ __forceinline__ void set_flag(int* p, int v) {
  __hip_atomic_store(p, v, __ATOMIC_RELAXED, __HIP_MEMORY_SCOPE_SYSTEM);
}

// wave-level wait: active lanes poll DENSELY-PACKED flags (4B stride) so the
// 12-lane poll coalesces into a single MALL line request per iteration.
__device__ __forceinline__ void wave_wait(const int* p, int tgt, bool active) {
  while (true) {
    int v = __hip_atomic_load(p, __ATOMIC_RELAXED, __HIP_MEMORY_SCOPE_SYSTEM);
    if (!__any(active && (v < tgt))) break;
    __builtin_amdgcn_s_sleep(1);
  }
}

// 12-subtile K-loop, FULL up-front prefetch (48 loads), exact FIFO vmcnt,
// AGPR-resident weights via asm MFMA. base includes wave K-offset + kg*8.
__device__ __forceinline__ void kloop12a(const u16* base, const bf16x8 (&Ba)[12][2],
                                         f32x4 (&acc)[4][2], int r16) {
  const u16* rp[4];
#pragma unroll
  for (int mf = 0; mf < 4; ++mf) rp[mf] = base + (size_t)(mf * 16 + r16) * 1536;
  bf16x8 A[12][4];
  WAITV(0);                                   // region entry: FIFO count = 0
#pragma unroll
  for (int d = 0; d < 12; ++d)
#pragma unroll
    for (int mf = 0; mf < 4; ++mf)
      LOAD_SC_OFS(A[d][mf], rp[mf], d * 64);
#pragma unroll
  for (int ks = 0; ks < 12; ++ks) {
    const int rem = 11 - ks;                  // compile-time after unroll
    if (rem == 11)      WAITV(44);
    else if (rem == 10) WAITV(40);
    else if (rem == 9)  WAITV(36);
    else if (rem == 8)  WAITV(32);
    else if (rem == 7)  WAITV(28);
    else if (rem == 6)  WAITV(24);
    else if (rem == 5)  WAITV(20);
    else if (rem == 4)  WAITV(16);
    else if (rem == 3)  WAITV(12);
    else if (rem == 2)  WAITV(8);
    else if (rem == 1)  WAITV(4);
    else                WAITV(0);
    __builtin_amdgcn_sched_barrier(0);
#pragma unroll
    for (int mf = 0; mf < 4; ++mf) {
      MFMA_AB(acc[mf][0], A[ks][mf], Ba[ks][0]);
      MFMA_AB(acc[mf][1], A[ks][mf], Ba[ks][1]);
    }
  }
  MFMA_FENCE();                               // asm MFMA -> VALU read hazard
}

// x path: cached fp32 loads + cvt, intrinsic MFMA (VGPR weights); x read-only
__device__ __forceinline__ void kloop_x4(const float* xb, const bf16x8 (&Br)[4][2],
                                         f32x4 (&acc)[4][2], int r16) {
#pragma unroll
  for (int ks = 0; ks < 4; ++ks)
#pragma unroll
    for (int mf = 0; mf < 4; ++mf) {
      bf16x8 a = cvt8(xb + (size_t)(mf * 16 + r16) * INSZ + ks * 32);
      acc[mf][0] = mfma16(a, Br[ks][0], acc[mf][0]);
      acc[mf][1] = mfma16(a, Br[ks][1], acc[mf][1]);
    }
}

__device__ __forceinline__ void store_red(float (*red)[64][36], int kw, int kg, int r16,
                                          const f32x4 (&acc)[4][2]) {
#pragma unroll
  for (int mf = 0; mf < 4; ++mf)
#pragma unroll
    for (int nf = 0; nf < 2; ++nf)
#pragma unroll
      for (int r = 0; r < 4; ++r)
        red[kw][mf * 16 + kg * 4 + r][nf * 16 + r16] = acc[mf][nf][r];
}

// sum 4 waves + bias (in regs), tanh, pack, 16B sc-store. 256 thr, 8 cols each.
__device__ __forceinline__ void epi_tanh(const float (*red)[64][36], f32x4 bv0, f32x4 bv1,
                                         u16* dstbase, int n0, int tid) {
  const int row = tid >> 2, c0 = (tid & 3) * 8;
  f32x4 s0 = bv0, s1 = bv1;
#pragma unroll
  for (int w = 0; w < 4; ++w) {
    s0 += *(const f32x4*)&red[w][row][c0];
    s1 += *(const f32x4*)&red[w][row][c0 + 4];
  }
  float t[8];
#pragma unroll
  for (int j = 0; j < 4; ++j) t[j] = tanhf(s0[j]);
#pragma unroll
  for (int j = 0; j < 4; ++j) t[4 + j] = tanhf(s1[j]);
  union { unsigned u[4]; bf16x8 v; } pk;
  asm("v_cvt_pk_bf16_f32 %0, %1, %2" : "=v"(pk.u[0]) : "v"(t[0]), "v"(t[1]));
  asm("v_cvt_pk_bf16_f32 %0, %1, %2" : "=v"(pk.u[1]) : "v"(t[2]), "v"(t[3]));
  asm("v_cvt_pk_bf16_f32 %0, %1, %2" : "=v"(pk.u[2]) : "v"(t[4]), "v"(t[5]));
  asm("v_cvt_pk_bf16_f32 %0, %1, %2" : "=v"(pk.u[3]) : "v"(t[6]), "v"(t[7]));
  u16* dst = dstbase + (size_t)row * 1536 + n0 + c0;
  STORE_SC(dst, pk.v);
}

__global__ __launch_bounds__(256)
__attribute__((amdgpu_waves_per_eu(1, 1)))
void rnn_main(
    const float* __restrict__ x,
    const u16* __restrict__ W1T, const u16* __restrict__ W2T, const u16* __restrict__ WoT,
    const float* __restrict__ b1, const float* __restrict__ b2, const float* __restrict__ bo,
    u16* __restrict__ h1ring, u16* __restrict__ h2ring,
    float* __restrict__ out, int* __restrict__ bar)
{
  __shared__ float red[4][64][36];            // 36 KB
  const int tid = threadIdx.x;
  const int kw = tid >> 6, lane = tid & 63;
  const int r16 = lane & 15, kg = lane >> 4;
  const int bid = blockIdx.x;

  int grp, half, col;
  if (bid < 2 * NC1)              { grp = 0; half = bid / NC1;         col = bid % NC1; }
  else if (bid < 2 * (NC1 + NC2)) { grp = 1; half = (bid - 96) / NC2;  col = (bid - 96) % NC2; }
  else                            { grp = 2; half = (bid - 192) / NC3; col = (bid - 192) % NC3; }
  const int n0 = col * 32;
  // DENSE flag regions: 4B stride, each group 64B-aligned, 64-int blocks.
  int* f1 = bar + half * 64;                  // 48 flags
  int* f2 = bar + 128 + half * 64;            // 48 flags
  int* f3 = bar + 256 + half * 64;            // 16 flags

  u16* h1base = h1ring + (size_t)half * RING * HALF_M * H1SZ;
  u16* h2base = h2ring + (size_t)half * RING * HALF_M * H2SZ;

  // ---- per-lane wait descriptors (dense flags -> coalesced polls) ----
  const int* wpA = f1; int dA = 0; bool aA = false;
  const int* wpB = f1; int dB = 0; bool aB = false;
  if (grp == 0) {                 // G1: fresh = f1 (h1[k-1]); back-pressure f2 >= k-6
    if (lane < 12)                  { wpA = f1 + kw * 12 + lane; dA = 0;  aA = true; }
    else if (kw == 0 && lane >= 16) { wpA = f2 + (lane - 16);    dA = -6; aA = true; }
  } else if (grp == 1) {          // G2: A = f2 (h2[j-1]) + ring f3; B = f1 (h1[j])
    if (lane < 12) {
      wpA = f2 + kw * 12 + lane; dA = 0; aA = true;
      wpB = f1 + kw * 12 + lane; dB = 1; aB = true;
    } else if (kw == 0 && lane >= 32 && lane < 48) {
      wpA = f3 + (lane - 32); dA = -6; aA = true;
    }
  } else {                        // G3: f2 >= j+1
    if (lane < 12)                  { wpA = f2 + kw * 12 + lane; dA = 1;  aA = true; }
  }

  if (grp == 0) {
    // ===== G1: h1[k] = tanh([x_k | h1[k-1]] @ W1 + b1) =====
    // wave kw: x cols [kw*128,+128) (VGPR weights), h cols [kw*384,+384) (AGPR)
    bf16x8 BrX[4][2], Brh[12][2];
#pragma unroll
    for (int ks = 0; ks < 4; ++ks)
#pragma unroll
      for (int nf = 0; nf < 2; ++nf)
        BrX[ks][nf] = *(const bf16x8*)(W1T + (size_t)(n0 + nf * 16 + r16) * K1
                                       + kw * 128 + ks * 32 + kg * 8);
#pragma unroll
    for (int ks = 0; ks < 12; ++ks)
#pragma unroll
      for (int nf = 0; nf < 2; ++nf)
        Brh[ks][nf] = *(const bf16x8*)(W1T + (size_t)(n0 + nf * 16 + r16) * K1
                                       + 512 + kw * 384 + ks * 32 + kg * 8);
#pragma unroll
    for (int ks = 0; ks < 4; ++ks) { PIN4(BrX[ks][0]); PIN4(BrX[ks][1]); }
#pragma unroll
    for (int ks = 0; ks < 12; ++ks) { PINA(Brh[ks][0]); PINA(Brh[ks][1]); }
    asm volatile("s_nop 7\n\ts_nop 7");       // accvgpr_write -> mfma-read fence
    const f32x4 bv0 = *(const f32x4*)(b1 + n0 + (tid & 3) * 8);
    const f32x4 bv1 = *(const f32x4*)(b1 + n0 + (tid & 3) * 8 + 4);

    for (int k = 0; k < STEPS; ++k) {
      f32x4 acc[4][2] = {};
      const float* xb = x + ((size_t)k * BATCH + half * HALF_M) * INSZ + kw * 128 + kg * 8;
      kloop_x4(xb, BrX, acc, r16);            // dependency-free, hides the poll
      wave_wait(wpA, k + dA, aA);             // h1[k-1] flags + ring back-pressure
      kloop12a(h1base + (size_t)((k + RING - 1) & (RING - 1)) * HALF_M * H1SZ
               + kw * 384 + kg * 8, Brh, acc, r16);
      store_red(red, kw, kg, r16, acc);
      __syncthreads();
      epi_tanh(red, bv0, bv1, h1base + (size_t)(k & (RING - 1)) * HALF_M * H1SZ, n0, tid);
      WAITV(0);
      __syncthreads();
      if (tid == 0) set_flag(&f1[col], k + 1);
    }
  } else if (grp == 1) {
    // ===== G2: h2[j] = tanh([h1[j] | h2[j-1]] @ W2 + b2) =====
    // OFF-CHAIN FIRST: h1[j]-part runs before the f2 self-chain wait, so the
    // critical cycle is only {detect f2 -> h2 kloop -> epi -> flag}.
    bf16x8 Bh1[12][2], Bh2[12][2];
#pragma unroll
    for (int ks = 0; ks < 12; ++ks)
#pragma unroll
      for (int nf = 0; nf < 2; ++nf) {
        Bh1[ks][nf] = *(const bf16x8*)(W2T + (size_t)(n0 + nf * 16 + r16) * K2
                                       + kw * 384 + ks * 32 + kg * 8);
        Bh2[ks][nf] = *(const bf16x8*)(W2T + (size_t)(n0 + nf * 16 + r16) * K2
                                       + 1536 + kw * 384 + ks * 32 + kg * 8);
      }
#pragma unroll
    for (int ks = 0; ks < 12; ++ks) { PINA(Bh1[ks][0]); PINA(Bh1[ks][1]);
                                      PINA(Bh2[ks][0]); PINA(Bh2[ks][1]); }
    asm volatile("s_nop 7\n\ts_nop 7");
    const f32x4 bv0 = *(const f32x4*)(b2 + n0 + (tid & 3) * 8);
    const f32x4 bv1 = *(const f32x4*)(b2 + n0 + (tid & 3) * 8 + 4);

    for (int j = 0; j < STEPS; ++j) {
      f32x4 acc[4][2] = {};
      wave_wait(wpB, j + dB, aB);             // h1[j] (G1 6 ahead -> pre-satisfied)
      kloop12a(h1base + (size_t)(j & (RING - 1)) * HALF_M * H1SZ
               + kw * 384 + kg * 8, Bh1, acc, r16);   // off-chain work
      wave_wait(wpA, j + dA, aA);             // h2[j-1] self-chain + ring f3
      kloop12a(h2base + (size_t)((j + RING - 1) & (RING - 1)) * HALF_M * H2SZ
               + kw * 384 + kg * 8, Bh2, acc, r16);   // on-chain work (minimal)
      store_red(red, kw, kg, r16, acc);
      __syncthreads();
      epi_tanh(red, bv0, bv1, h2base + (size_t)(j & (RING - 1)) * HALF_M * H2SZ, n0, tid);
      WAITV(0);
      __syncthreads();
      if (tid == 0) set_flag(&f2[col], j + 1);
    }
  } else {
    // ===== G3: out[j+1] = h2[j] @ Wo + bo; wave kw: h2 cols [kw*384,+384)
    bf16x8 Br[12][2];
#pragma unroll
    for (int ks = 0; ks < 12; ++ks)
#pragma unroll
      for (int nf = 0; nf < 2; ++nf)
        Br[ks][nf] = *(const bf16x8*)(WoT + (size_t)(n0 + nf * 16 + r16) * H2SZ
                                      + kw * 384 + ks * 32 + kg * 8);
#pragma unroll
    for (int ks = 0; ks < 12; ++ks) { PINA(Br[ks][0]); PINA(Br[ks][1]); }
    asm volatile("s_nop 7\n\ts_nop 7");
    const f32x4 bv0 = *(const f32x4*)(bo + n0 + (tid & 3) * 8);
    const f32x4 bv1 = *(const f32x4*)(bo + n0 + (tid & 3) * 8 + 4);

    for (int j = 0; j < STEPS; ++j) {
      f32x4 acc[4][2] = {};
      wave_wait(wpA, j + dA, aA);             // h2[j] (G2 ahead -> near-instant)
      kloop12a(h2base + (size_t)(j & (RING - 1)) * HALF_M * H2SZ
               + kw * 384 + kg * 8, Br, acc, r16);
      store_red(red, kw, kg, r16, acc);
      __syncthreads();
      {
        const int row = tid >> 2, c0 = (tid & 3) * 8;
        f32x4 s0 = bv0, s1 = bv1;
#pragma unroll
        for (int w = 0; w < 4; ++w) {
          s0 += *(const f32x4*)&red[w][row][c0];
          s1 += *(const f32x4*)&red[w][row][c0 + 4];
        }
        float* dst = out + ((size_t)(j + 1) * BATCH + half * HALF_M + row) * NOUT + n0 + c0;
        *(f32x4*)dst = s0;
        *(f32x4*)(dst + 4) = s1;
      }
      __syncthreads();                        // h2 reads retired before signaling
      if (tid == 0) set_flag(&f3[col], j + 1);
    }
  }
}

// LDS-tiled transpose + fp32->bf16:  dst[n*K + k] = bf16(src[k*N + n])
__global__ void transpose_cvt(const float* __restrict__ src, u16* __restrict__ dst, int K, int N) {
  __shared__ u16 tile[32][33];
  int kb = blockIdx.x * 32, nb = blockIdx.y * 32;
  int tx = threadIdx.x & 31, ty = threadIdx.x >> 5;
  for (int i = ty; i < 32; i += 8)
    tile[i][tx] = f2bf(src[(size_t)(kb + i) * N + nb + tx]);
  __syncthreads();
  for (int i = ty; i < 32; i += 8)
    dst[(size_t)(nb + i) * K + kb + tx] = tile[tx][i];
}

extern "C" void kernel_launch(void* const* d_in, const int* in_sizes, int n_in,
                              void* d_out, int out_size, void* d_ws, size_t ws_size,
                              hipStream_t stream) {
  const float* x  = (const float*)d_in[0];
  const float* W1 = (const float*)d_in[1];
  const float* b1 = (const float*)d_in[2];
  const float* W2 = (const float*)d_in[3];
  const float* b2 = (const float*)d_in[4];
  const float* Wo = (const float*)d_in[5];
  const float* bo = (const float*)d_in[6];
  float* out = (float*)d_out;
  char*  ws  = (char*)d_ws;

  u16* W1T    = (u16*)(ws);                 // 2048*1536*2 = 6291456
  u16* W2T    = (u16*)(ws + 6291456);       // 3072*1536*2 = 9437184
  u16* WoT    = (u16*)(ws + 15728640);      // 1536* 512*2 = 1572864
  u16* h1ring = (u16*)(ws + 17301504);      // 2 halves * 8 slots * 64*1536*2 = 3145728
  u16* h2ring = (u16*)(ws + 20447232);      // 3145728
  int* bar    = (int*)(ws + 23592960);      // dense flags: 384 ints used

  hipMemsetAsync(ws + 17301504, 0, 3145728 * 2 + 14336, stream);
  hipMemsetAsync(d_out, 0, (size_t)BATCH * NOUT * sizeof(float), stream);

  transpose_cvt<<<dim3(K1 / 32, H1SZ / 32), 256, 0, stream>>>(W1, W1T, K1, H1SZ);
  transpose_cvt<<<dim3(K2 / 32, H1SZ / 32), 256, 0, stream>>>(W2, W2T, K2, H1SZ);
  transpose_cvt<<<dim3(H2SZ / 32, NOUT / 32), 256, 0, stream>>>(Wo, WoT, H2SZ, NOUT);

  rnn_main<<<NBLK, 256, 0, stream>>>(x, W1T, W2T, WoT, b1, b2, bo, h1ring, h2ring, out, bar);
}

// Round 18
// 3229.511 us; speedup vs baseline: 1.0955x; 1.0955x over previous
//
#include <hip/hip_runtime.h>
#include <math.h>

#define STEPS 256
#define BATCH 128
#define HALF_M 64
#define INSZ  512
#define H1SZ  1536
#define H2SZ  1536
#define NOUT  512
#define K1    2048   // INSZ + H1SZ
#define K2    3072   // H1SZ + H2SZ
#define NC1   48     // col-blocks per half (32 cols each)
#define NC2   48
#define NC3   16
#define NBLK  224    // 2 halves * (48+48+16)
#define RING  8

typedef short bf16x8 __attribute__((ext_vector_type(8)));
typedef float f32x4  __attribute__((ext_vector_type(4)));
typedef unsigned short u16;

__device__ __forceinline__ f32x4 mfma16(bf16x8 a, bf16x8 b, f32x4 c) {
  return __builtin_amdgcn_mfma_f32_16x16x32_bf16(a, b, c, 0, 0, 0);
}

__device__ __forceinline__ u16 f2bf(float f) {
  unsigned u = __builtin_bit_cast(unsigned, f);
  u += 0x7fffu + ((u >> 16) & 1u);
  return (u16)(u >> 16);
}

// 8 fp32 -> bf16x8 (RTNE) via packed cvt (register-only asm)
__device__ __forceinline__ bf16x8 cvt8(const float* p) {
  f32x4 lo = *(const f32x4*)p;
  f32x4 hi = *(const f32x4*)(p + 4);
  union { unsigned u[4]; bf16x8 v; } r;
  asm("v_cvt_pk_bf16_f32 %0, %1, %2" : "=v"(r.u[0]) : "v"(lo[0]), "v"(lo[1]));
  asm("v_cvt_pk_bf16_f32 %0, %1, %2" : "=v"(r.u[1]) : "v"(lo[2]), "v"(lo[3]));
  asm("v_cvt_pk_bf16_f32 %0, %1, %2" : "=v"(r.u[2]) : "v"(hi[0]), "v"(hi[1]));
  asm("v_cvt_pk_bf16_f32 %0, %1, %2" : "=v"(r.u[3]) : "v"(hi[2]), "v"(hi[3]));
  return r.v;
}

// ---- sealed async-load region primitives ----
#define LOAD_SC_OFS(dst, ptr, ofs) \
  asm volatile("global_load_dwordx4 %0, %1, off offset:%2 sc0 sc1" \
               : "=v"(dst) : "v"(ptr), "i"(ofs) : "memory")
#define STORE_SC(ptr, val) \
  asm volatile("global_store_dwordx4 %0, %1, off sc0 sc1" :: "v"(ptr), "v"(val) : "memory")
#define WAITV(n) asm volatile("s_waitcnt vmcnt(" #n ")" ::: "memory")
#define PIN4(v)  asm volatile("" : "+v"(v))
#define PINA(v)  asm volatile("" : "+a"(v))      // force value into AGPRs
// MFMA with B-operand in AGPR (frees VGPR budget); C/D chained in VGPR
#define MFMA_AB(acc, va, ab) \
  asm volatile("v_mfma_f32_16x16x32_bf16 %0, %1, %2, %0" : "+v"(acc) : "v"(va), "a"(ab))
#define MFMA_FENCE() asm volatile("s_nop 7\n\ts_nop 7\n\ts_nop 7")

__device__ __forceinline__ void set_flag(int* p, int v) {
  __hip_atomic_store(p, v, __ATOMIC_RELAXED, __HIP_MEMORY_SCOPE_SYSTEM);
}

// wave-level wait: each active lane polls its own flag until >= tgt.
__device__ __forceinline__ void wave_wait(const int* p, int tgt, bool active) {
  while (true) {
    int v = __hip_atomic_load(p, __ATOMIC_RELAXED, __HIP_MEMORY_SCOPE_SYSTEM);
    if (!__any(active && (v < tgt))) break;
    __builtin_amdgcn_s_sleep(1);
  }
}

// 12-subtile K-loop, FULL up-front prefetch (48 loads), exact FIFO vmcnt,
// AGPR-resident weights via asm MFMA. base includes wave K-offset + kg*8.
__device__ __forceinline__ void kloop12a(const u16* base, const bf16x8 (&Ba)[12][2],
                                         f32x4 (&acc)[4][2], int r16) {
  const u16* rp[4];
#pragma unroll
  for (int mf = 0; mf < 4; ++mf) rp[mf] = base + (size_t)(mf * 16 + r16) * 1536;
  bf16x8 A[12][4];
  WAITV(0);                                   // region entry: FIFO count = 0
#pragma unroll
  for (int d = 0; d < 12; ++d)
#pragma unroll
    for (int mf = 0; mf < 4; ++mf)
      LOAD_SC_OFS(A[d][mf], rp[mf], d * 64);
#pragma unroll
  for (int ks = 0; ks < 12; ++ks) {
    const int rem = 11 - ks;                  // compile-time after unroll
    if (rem == 11)      WAITV(44);
    else if (rem == 10) WAITV(40);
    else if (rem == 9)  WAITV(36);
    else if (rem == 8)  WAITV(32);
    else if (rem == 7)  WAITV(28);
    else if (rem == 6)  WAITV(24);
    else if (rem == 5)  WAITV(20);
    else if (rem == 4)  WAITV(16);
    else if (rem == 3)  WAITV(12);
    else if (rem == 2)  WAITV(8);
    else if (rem == 1)  WAITV(4);
    else                WAITV(0);
    __builtin_amdgcn_sched_barrier(0);
#pragma unroll
    for (int mf = 0; mf < 4; ++mf) {
      MFMA_AB(acc[mf][0], A[ks][mf], Ba[ks][0]);
      MFMA_AB(acc[mf][1], A[ks][mf], Ba[ks][1]);
    }
  }
  MFMA_FENCE();                               // asm MFMA -> VALU read hazard
}

// x path: cached fp32 loads + cvt, intrinsic MFMA (VGPR weights); x read-only
__device__ __forceinline__ void kloop_x4(const float* xb, const bf16x8 (&Br)[4][2],
                                         f32x4 (&acc)[4][2], int r16) {
#pragma unroll
  for (int ks = 0; ks < 4; ++ks)
#pragma unroll
    for (int mf = 0; mf < 4; ++mf) {
      bf16x8 a = cvt8(xb + (size_t)(mf * 16 + r16) * INSZ + ks * 32);
      acc[mf][0] = mfma16(a, Br[ks][0], acc[mf][0]);
      acc[mf][1] = mfma16(a, Br[ks][1], acc[mf][1]);
    }
}

__device__ __forceinline__ void store_red(float (*red)[64][36], int kw, int kg, int r16,
                                          const f32x4 (&acc)[4][2]) {
#pragma unroll
  for (int mf = 0; mf < 4; ++mf)
#pragma unroll
    for (int nf = 0; nf < 2; ++nf)
#pragma unroll
      for (int r = 0; r < 4; ++r)
        red[kw][mf * 16 + kg * 4 + r][nf * 16 + r16] = acc[mf][nf][r];
}

// sum 4 waves + bias (in regs), tanh, pack, 16B sc-store. 256 thr, 8 cols each.
__device__ __forceinline__ void epi_tanh(const float (*red)[64][36], f32x4 bv0, f32x4 bv1,
                                         u16* dstbase, int n0, int tid) {
  const int row = tid >> 2, c0 = (tid & 3) * 8;
  f32x4 s0 = bv0, s1 = bv1;
#pragma unroll
  for (int w = 0; w < 4; ++w) {
    s0 += *(const f32x4*)&red[w][row][c0];
    s1 += *(const f32x4*)&red[w][row][c0 + 4];
  }
  float t[8];
#pragma unroll
  for (int j = 0; j < 4; ++j) t[j] = tanhf(s0[j]);
#pragma unroll
  for (int j = 0; j < 4; ++j) t[4 + j] = tanhf(s1[j]);
  union { unsigned u[4]; bf16x8 v; } pk;
  asm("v_cvt_pk_bf16_f32 %0, %1, %2" : "=v"(pk.u[0]) : "v"(t[0]), "v"(t[1]));
  asm("v_cvt_pk_bf16_f32 %0, %1, %2" : "=v"(pk.u[1]) : "v"(t[2]), "v"(t[3]));
  asm("v_cvt_pk_bf16_f32 %0, %1, %2" : "=v"(pk.u[2]) : "v"(t[4]), "v"(t[5]));
  asm("v_cvt_pk_bf16_f32 %0, %1, %2" : "=v"(pk.u[3]) : "v"(t[6]), "v"(t[7]));
  u16* dst = dstbase + (size_t)row * 1536 + n0 + c0;
  STORE_SC(dst, pk.v);
}

__global__ __launch_bounds__(256)
__attribute__((amdgpu_waves_per_eu(1, 1)))
void rnn_main(
    const float* __restrict__ x,
    const u16* __restrict__ W1T, const u16* __restrict__ W2T, const u16* __restrict__ WoT,
    const float* __restrict__ b1, const float* __restrict__ b2, const float* __restrict__ bo,
    u16* __restrict__ h1ring, u16* __restrict__ h2ring,
    float* __restrict__ out, int* __restrict__ bar)
{
  __shared__ float red[4][64][36];            // 36 KB
  const int tid = threadIdx.x;
  const int kw = tid >> 6, lane = tid & 63;
  const int r16 = lane & 15, kg = lane >> 4;
  const int bid = blockIdx.x;

  int grp, half, col;
  if (bid < 2 * NC1)              { grp = 0; half = bid / NC1;         col = bid % NC1; }
  else if (bid < 2 * (NC1 + NC2)) { grp = 1; half = (bid - 96) / NC2;  col = (bid - 96) % NC2; }
  else                            { grp = 2; half = (bid - 192) / NC3; col = (bid - 192) % NC3; }
  const int n0 = col * 32;
  int* f1 = bar + (half * NC1) * 16;
  int* f2 = bar + (96 + half * NC2) * 16;
  int* f3 = bar + (192 + half * NC3) * 16;

  u16* h1base = h1ring + (size_t)half * RING * HALF_M * H1SZ;
  u16* h2base = h2ring + (size_t)half * RING * HALF_M * H2SZ;

  // ---- per-lane wait descriptors ----
  const int* wpA = f1; int dA = 0; bool aA = false;
  const int* wpB = f1; int dB = 0; bool aB = false;
  if (grp == 0) {                 // G1: fresh = f1 (h1[k-1]); back-pressure f2 >= k-6
    if (lane < 12)                  { wpA = f1 + (kw * 12 + lane) * 16; dA = 0;  aA = true; }
    else if (kw == 0 && lane >= 16) { wpA = f2 + (lane - 16) * 16;      dA = -6; aA = true; }
  } else if (grp == 1) {          // G2: A = f2 (h2[j-1]) + ring f3; B = f1 (h1[j])
    if (lane < 12) {
      wpA = f2 + (kw * 12 + lane) * 16; dA = 0; aA = true;
      wpB = f1 + (kw * 12 + lane) * 16; dB = 1; aB = true;
    } else if (kw == 0 && lane >= 32 && lane < 48) {
      wpA = f3 + (lane - 32) * 16; dA = -6; aA = true;
    }
  } else {                        // G3: f2 >= j+1
    if (lane < 12)                  { wpA = f2 + (kw * 12 + lane) * 16; dA = 1;  aA = true; }
  }

  if (grp == 0) {
    // ===== G1: h1[k] = tanh([x_k | h1[k-1]] @ W1 + b1) =====
    // wave kw: x cols [kw*128,+128) (VGPR weights), h cols [kw*384,+384) (AGPR)
    bf16x8 BrX[4][2], Brh[12][2];
#pragma unroll
    for (int ks = 0; ks < 4; ++ks)
#pragma unroll
      for (int nf = 0; nf < 2; ++nf)
        BrX[ks][nf] = *(const bf16x8*)(W1T + (size_t)(n0 + nf * 16 + r16) * K1
                                       + kw * 128 + ks * 32 + kg * 8);
#pragma unroll
    for (int ks = 0; ks < 12; ++ks)
#pragma unroll
      for (int nf = 0; nf < 2; ++nf)
        Brh[ks][nf] = *(const bf16x8*)(W1T + (size_t)(n0 + nf * 16 + r16) * K1
                                       + 512 + kw * 384 + ks * 32 + kg * 8);
#pragma unroll
    for (int ks = 0; ks < 4; ++ks) { PIN4(BrX[ks][0]); PIN4(BrX[ks][1]); }
#pragma unroll
    for (int ks = 0; ks < 12; ++ks) { PINA(Brh[ks][0]); PINA(Brh[ks][1]); }
    asm volatile("s_nop 7\n\ts_nop 7");       // accvgpr_write -> mfma-read fence
    const f32x4 bv0 = *(const f32x4*)(b1 + n0 + (tid & 3) * 8);
    const f32x4 bv1 = *(const f32x4*)(b1 + n0 + (tid & 3) * 8 + 4);

    for (int k = 0; k < STEPS; ++k) {
      f32x4 acc[4][2] = {};
      const float* xb = x + ((size_t)k * BATCH + half * HALF_M) * INSZ + kw * 128 + kg * 8;
      kloop_x4(xb, BrX, acc, r16);            // dependency-free, hides the poll
      wave_wait(wpA, k + dA, aA);             // h1[k-1] flags + ring back-pressure
      kloop12a(h1base + (size_t)((k + RING - 1) & (RING - 1)) * HALF_M * H1SZ
               + kw * 384 + kg * 8, Brh, acc, r16);
      store_red(red, kw, kg, r16, acc);
      __syncthreads();
      epi_tanh(red, bv0, bv1, h1base + (size_t)(k & (RING - 1)) * HALF_M * H1SZ, n0, tid);
      WAITV(0);
      __syncthreads();
      if (tid == 0) set_flag(&f1[col * 16], k + 1);
    }
  } else if (grp == 1) {
    // ===== G2: h2[j] = tanh([h1[j] | h2[j-1]] @ W2 + b2) =====
    // OFF-CHAIN FIRST: h1[j]-part runs before the f2 self-chain wait, so the
    // critical cycle is only {detect f2 -> h2 kloop -> epi -> flag}.
    bf16x8 Bh1[12][2], Bh2[12][2];
#pragma unroll
    for (int ks = 0; ks < 12; ++ks)
#pragma unroll
      for (int nf = 0; nf < 2; ++nf) {
        Bh1[ks][nf] = *(const bf16x8*)(W2T + (size_t)(n0 + nf * 16 + r16) * K2
                                       + kw * 384 + ks * 32 + kg * 8);
        Bh2[ks][nf] = *(const bf16x8*)(W2T + (size_t)(n0 + nf * 16 + r16) * K2
                                       + 1536 + kw * 384 + ks * 32 + kg * 8);
      }
#pragma unroll
    for (int ks = 0; ks < 12; ++ks) { PINA(Bh1[ks][0]); PINA(Bh1[ks][1]);
                                      PINA(Bh2[ks][0]); PINA(Bh2[ks][1]); }
    asm volatile("s_nop 7\n\ts_nop 7");
    const f32x4 bv0 = *(const f32x4*)(b2 + n0 + (tid & 3) * 8);
    const f32x4 bv1 = *(const f32x4*)(b2 + n0 + (tid & 3) * 8 + 4);

    for (int j = 0; j < STEPS; ++j) {
      f32x4 acc[4][2] = {};
      wave_wait(wpB, j + dB, aB);             // h1[j] (G1 6 ahead -> pre-satisfied)
      kloop12a(h1base + (size_t)(j & (RING - 1)) * HALF_M * H1SZ
               + kw * 384 + kg * 8, Bh1, acc, r16);   // off-chain work
      wave_wait(wpA, j + dA, aA);             // h2[j-1] self-chain + ring f3
      kloop12a(h2base + (size_t)((j + RING - 1) & (RING - 1)) * HALF_M * H2SZ
               + kw * 384 + kg * 8, Bh2, acc, r16);   // on-chain work (minimal)
      store_red(red, kw, kg, r16, acc);
      __syncthreads();
      epi_tanh(red, bv0, bv1, h2base + (size_t)(j & (RING - 1)) * HALF_M * H2SZ, n0, tid);
      WAITV(0);
      __syncthreads();
      if (tid == 0) set_flag(&f2[col * 16], j + 1);
    }
  } else {
    // ===== G3: out[j+1] = h2[j] @ Wo + bo; wave kw: h2 cols [kw*384,+384)
    bf16x8 Br[12][2];
#pragma unroll
    for (int ks = 0; ks < 12; ++ks)
#pragma unroll
      for (int nf = 0; nf < 2; ++nf)
        Br[ks][nf] = *(const bf16x8*)(WoT + (size_t)(n0 + nf * 16 + r16) * H2SZ
                                      + kw * 384 + ks * 32 + kg * 8);
#pragma unroll
    for (int ks = 0; ks < 12; ++ks) { PINA(Br[ks][0]); PINA(Br[ks][1]); }
    asm volatile("s_nop 7\n\ts_nop 7");
    const f32x4 bv0 = *(const f32x4*)(bo + n0 + (tid & 3) * 8);
    const f32x4 bv1 = *(const f32x4*)(bo + n0 + (tid & 3) * 8 + 4);

    for (int j = 0; j < STEPS; ++j) {
      f32x4 acc[4][2] = {};
      wave_wait(wpA, j + dA, aA);             // h2[j] (G2 ahead -> near-instant)
      kloop12a(h2base + (size_t)(j & (RING - 1)) * HALF_M * H2SZ
               + kw * 384 + kg * 8, Br, acc, r16);
      store_red(red, kw, kg, r16, acc);
      __syncthreads();
      {
        const int row = tid >> 2, c0 = (tid & 3) * 8;
        f32x4 s0 = bv0, s1 = bv1;
#pragma unroll
        for (int w = 0; w < 4; ++w) {
          s0 += *(const f32x4*)&red[w][row][c0];
          s1 += *(const f32x4*)&red[w][row][c0 + 4];
        }
        float* dst = out + ((size_t)(j + 1) * BATCH + half * HALF_M + row) * NOUT + n0 + c0;
        *(f32x4*)dst = s0;
        *(f32x4*)(dst + 4) = s1;
      }
      __syncthreads();                        // h2 reads retired before signaling
      if (tid == 0) set_flag(&f3[col * 16], j + 1);
    }
  }
}

// LDS-tiled transpose + fp32->bf16:  dst[n*K + k] = bf16(src[k*N + n])
__global__ void transpose_cvt(const float* __restrict__ src, u16* __restrict__ dst, int K, int N) {
  __shared__ u16 tile[32][33];
  int kb = blockIdx.x * 32, nb = blockIdx.y * 32;
  int tx = threadIdx.x & 31, ty = threadIdx.x >> 5;
  for (int i = ty; i < 32; i += 8)
    tile[i][tx] = f2bf(src[(size_t)(kb + i) * N + nb + tx]);
  __syncthreads();
  for (int i = ty; i < 32; i += 8)
    dst[(size_t)(nb + i) * K + kb + tx] = tile[tx][i];
}

extern "C" void kernel_launch(void* const* d_in, const int* in_sizes, int n_in,
                              void* d_out, int out_size, void* d_ws, size_t ws_size,
                              hipStream_t stream) {
  const float* x  = (const float*)d_in[0];
  const float* W1 = (const float*)d_in[1];
  const float* b1 = (const float*)d_in[2];
  const float* W2 = (const float*)d_in[3];
  const float* b2 = (const float*)d_in[4];
  const float* Wo = (const float*)d_in[5];
  const float* bo = (const float*)d_in[6];
  float* out = (float*)d_out;
  char*  ws  = (char*)d_ws;

  u16* W1T    = (u16*)(ws);                 // 2048*1536*2 = 6291456
  u16* W2T    = (u16*)(ws + 6291456);       // 3072*1536*2 = 9437184
  u16* WoT    = (u16*)(ws + 15728640);      // 1536* 512*2 = 1572864
  u16* h1ring = (u16*)(ws + 17301504);      // 2 halves * 8 slots * 64*1536*2 = 3145728
  u16* h2ring = (u16*)(ws + 20447232);      // 3145728
  int* bar    = (int*)(ws + 23592960);      // 224 flags * 64B = 14336

  hipMemsetAsync(ws + 17301504, 0, 3145728 * 2 + 14336, stream);
  hipMemsetAsync(d_out, 0, (size_t)BATCH * NOUT * sizeof(float), stream);

  transpose_cvt<<<dim3(K1 / 32, H1SZ / 32), 256, 0, stream>>>(W1, W1T, K1, H1SZ);
  transpose_cvt<<<dim3(K2 / 32, H1SZ / 32), 256, 0, stream>>>(W2, W2T, K2, H1SZ);
  transpose_cvt<<<dim3(H2SZ / 32, NOUT / 32), 256, 0, stream>>>(Wo, WoT, H2SZ, NOUT);

  rnn_main<<<NBLK, 256, 0, stream>>>(x, W1T, W2T, WoT, b1, b2, bo, h1ring, h2ring, out, bar);
}